// Round 12
// baseline (1057.360 us; speedup 1.0000x reference)
//
#include <hip/hip_runtime.h>
#include <math.h>

#define DEV __device__ __forceinline__

static const int N_LOW = 5000, N_HIGH = 50000, E_LH = 200000, E_HH = 400000;
static const int E2 = E_HH + N_HIGH;   // 450000 with self loops
static const int ETOT = E_LH + E2;     // 650000 combined
static const int RBLK = 2048;          // bn stage-1 blocks

typedef __attribute__((ext_vector_type(8))) short bf16x8;
typedef __attribute__((ext_vector_type(4))) float f32x4;
typedef unsigned short u16;

DEV short f2bf(float v) {            // round-to-nearest-even f32 -> bf16
    unsigned u = __float_as_uint(v);
    u += 0x7FFFu + ((u >> 16) & 1u);
    return (short)(u >> 16);
}
DEV float bf2f(u16 u) { return __uint_as_float(((unsigned)u) << 16); }

template <int VPL> struct RawTT { using T = u16; };
template <> struct RawTT<4> { using T = ushort4; };

// =================== MFMA GEMM on fragment-ordered operands =================
template <bool RELU, bool BF16OUT>
DEV void gemm_body(const bf16x8* __restrict__ Af, const bf16x8* __restrict__ Bf,
                   const float* __restrict__ bias, float* __restrict__ C,
                   int M, int N, int nkt) {
    const int l = threadIdx.x & 63;
    const int w = threadIdx.x >> 6;
    const int nt0 = blockIdx.x * 4;
    const int mt0 = blockIdx.y * 8 + w * 2;
    f32x4 acc[2][4];
#pragma unroll
    for (int i = 0; i < 2; i++)
#pragma unroll
        for (int j = 0; j < 4; j++) acc[i][j] = (f32x4){0.f, 0.f, 0.f, 0.f};
    const bf16x8* a0p = Af + (size_t)mt0 * nkt * 64 + l;
    const bf16x8* a1p = a0p + (size_t)nkt * 64;
    const bf16x8* bp = Bf + (size_t)nt0 * nkt * 64 + l;
    for (int kt = 0; kt < nkt; kt++) {
        bf16x8 a0 = a0p[kt * 64];
        bf16x8 a1 = a1p[kt * 64];
        bf16x8 b0 = bp[kt * 64];
        bf16x8 b1 = bp[(size_t)(nkt + kt) * 64];
        bf16x8 b2 = bp[(size_t)(2 * nkt + kt) * 64];
        bf16x8 b3 = bp[(size_t)(3 * nkt + kt) * 64];
        acc[0][0] = __builtin_amdgcn_mfma_f32_16x16x32_bf16(a0, b0, acc[0][0], 0, 0, 0);
        acc[0][1] = __builtin_amdgcn_mfma_f32_16x16x32_bf16(a0, b1, acc[0][1], 0, 0, 0);
        acc[0][2] = __builtin_amdgcn_mfma_f32_16x16x32_bf16(a0, b2, acc[0][2], 0, 0, 0);
        acc[0][3] = __builtin_amdgcn_mfma_f32_16x16x32_bf16(a0, b3, acc[0][3], 0, 0, 0);
        acc[1][0] = __builtin_amdgcn_mfma_f32_16x16x32_bf16(a1, b0, acc[1][0], 0, 0, 0);
        acc[1][1] = __builtin_amdgcn_mfma_f32_16x16x32_bf16(a1, b1, acc[1][1], 0, 0, 0);
        acc[1][2] = __builtin_amdgcn_mfma_f32_16x16x32_bf16(a1, b2, acc[1][2], 0, 0, 0);
        acc[1][3] = __builtin_amdgcn_mfma_f32_16x16x32_bf16(a1, b3, acc[1][3], 0, 0, 0);
    }
    const int colb = nt0 * 16 + (l & 15);
    const int rsub = (l >> 4) * 4;
#pragma unroll
    for (int mi = 0; mi < 2; mi++) {
        int rowb = (mt0 + mi) * 16 + rsub;
#pragma unroll
        for (int r = 0; r < 4; r++) {
            int row = rowb + r;
            if (row >= M) continue;
#pragma unroll
            for (int n = 0; n < 4; n++) {
                int col = colb + n * 16;
                float v = acc[mi][n][r] + bias[col];
                if (RELU) v = fmaxf(v, 0.f);
                if (BF16OUT)
                    ((u16*)C)[(size_t)row * N + col] = (u16)f2bf(v);
                else
                    C[(size_t)row * N + col] = v;
            }
        }
    }
}

template <bool RELU, bool BF16OUT>
__global__ __launch_bounds__(256) void gemm_mfma(
    const bf16x8* __restrict__ Af, const bf16x8* __restrict__ Bf,
    const float* __restrict__ bias, float* __restrict__ C,
    int M, int N, int nkt) {
    gemm_body<RELU, BF16OUT>(Af, Bf, bias, C, M, N, nkt);
}

// paired variant: blockIdx.z selects (Bf0,bias0,C0) or (Bf1,bias1,C1); same A.
__global__ __launch_bounds__(256) void gemm_mfma2(
    const bf16x8* __restrict__ Af,
    const bf16x8* __restrict__ Bf0, const bf16x8* __restrict__ Bf1,
    const float* __restrict__ bias0, const float* __restrict__ bias1,
    float* __restrict__ C0, float* __restrict__ C1,
    int M, int N, int nkt) {
    if (blockIdx.z == 0)
        gemm_body<false, true>(Af, Bf0, bias0, C0, M, N, nkt);
    else
        gemm_body<false, true>(Af, Bf1, bias1, C1, M, N, nkt);
}

// --------- BN-apply (stats from raw sums) + (relu) + bf16 frag cast --------
template <bool RELU>
__global__ __launch_bounds__(256) void bn_frag(
    const u16* __restrict__ x, int Nrows, int F,
    const float* __restrict__ sums,
    const float* __restrict__ g, const float* __restrict__ b,
    bf16x8* __restrict__ Af, int nmt, int nkt) {
    int total = nmt * nkt * 64;
    for (int idx = blockIdx.x * blockDim.x + threadIdx.x; idx < total;
         idx += gridDim.x * blockDim.x) {
        int mt = idx / (nkt * 64);
        int rem = idx - mt * (nkt * 64);
        int kt = rem >> 6, l = rem & 63;
        int row = mt * 16 + (l & 15);
        int colb = kt * 32 + (l >> 4) * 8;
        bf16x8 o;
#pragma unroll
        for (int j = 0; j < 8; j++) {
            int col = colb + j;
            float v = 0.f;
            if (row < Nrows && col < F) {
                float mu = sums[col] / Nrows;
                float var = sums[F + col] / Nrows - mu * mu;
                float istd = rsqrtf(fmaxf(var, 0.f) + 1e-5f);
                v = (bf2f(x[(size_t)row * F + col]) - mu) * istd * g[col] + b[col];
                if (RELU) v = fmaxf(v, 0.f);
            }
            o[j] = f2bf(v);
        }
        Af[idx] = o;
    }
}

// --------- plain cast (xl f32) into fragment-ordered A, zero-padded --------
__global__ __launch_bounds__(256) void cast_frag(
    const float* __restrict__ x, int Nrows, int F,
    bf16x8* __restrict__ Af, int nmt, int nkt) {
    int total = nmt * nkt * 64;
    for (int idx = blockIdx.x * blockDim.x + threadIdx.x; idx < total;
         idx += gridDim.x * blockDim.x) {
        int mt = idx / (nkt * 64);
        int rem = idx - mt * (nkt * 64);
        int kt = rem >> 6, l = rem & 63;
        int row = mt * 16 + (l & 15);
        int colb = kt * 32 + (l >> 4) * 8;
        bf16x8 o;
#pragma unroll
        for (int j = 0; j < 8; j++) {
            int col = colb + j;
            o[j] = (row < Nrows && col < F) ? f2bf(x[(size_t)row * F + col]) : (short)0;
        }
        Af[idx] = o;
    }
}

// --------- ALL weight [K][N] -> fragment-ordered B transforms in one -------
struct WtJobs {
    const float* W[8];
    bf16x8* out[8];
    int K[8], Nn[8], nnt[8], nkt[8];
};
__global__ __launch_bounds__(256) void wt_frag_all(WtJobs jobs) {
    const int job = blockIdx.y;
    const float* W = jobs.W[job];
    bf16x8* Bf = jobs.out[job];
    const int K = jobs.K[job], N = jobs.Nn[job];
    const int nkt = jobs.nkt[job];
    int total = jobs.nnt[job] * nkt * 64;
    for (int idx = blockIdx.x * blockDim.x + threadIdx.x; idx < total;
         idx += gridDim.x * blockDim.x) {
        int nt = idx / (nkt * 64);
        int rem = idx - nt * (nkt * 64);
        int kt = rem >> 6, l = rem & 63;
        int col = nt * 16 + (l & 15);
        int kb = kt * 32 + (l >> 4) * 8;
        bf16x8 o;
#pragma unroll
        for (int j = 0; j < 8; j++) {
            int k = kb + j;
            o[j] = (k < K && col < N) ? f2bf(W[(size_t)k * N + col]) : (short)0;
        }
        Bf[idx] = o;
    }
}

// ------------- combined CSR build over BOTH edge sets ----------------------
__global__ __launch_bounds__(256) void hist_all(
    const int* __restrict__ di_lh, const int* __restrict__ di_hh,
    int* __restrict__ cnt) {
    for (int i = blockIdx.x * blockDim.x + threadIdx.x; i < ETOT;
         i += gridDim.x * blockDim.x) {
        if (i < E_LH) {
            atomicAdd(&cnt[di_lh[i]], 1);
        } else {
            int j = i - E_LH;
            int d = (j < E_HH) ? di_hh[j] : (j - E_HH);
            atomicAdd(&cnt[N_HIGH + d], 1);
        }
    }
}

// ---- parallel exclusive scan over n ints (3 kernels, chunks of 1024) -------
__global__ __launch_bounds__(256) void scan_partial(
    const int* __restrict__ cnt, int* __restrict__ off,
    int* __restrict__ bsum, int n) {
    __shared__ int s[256];
    const int t = threadIdx.x;
    const int base = blockIdx.x * 1024 + t * 4;
    int v0 = (base < n) ? cnt[base] : 0;
    int v1 = (base + 1 < n) ? cnt[base + 1] : 0;
    int v2 = (base + 2 < n) ? cnt[base + 2] : 0;
    int v3 = (base + 3 < n) ? cnt[base + 3] : 0;
    int tsum = v0 + v1 + v2 + v3;
    s[t] = tsum;
    __syncthreads();
    for (int step = 1; step < 256; step <<= 1) {
        int q = (t >= step) ? s[t - step] : 0;
        __syncthreads();
        s[t] += q;
        __syncthreads();
    }
    int excl = s[t] - tsum;
    if (base < n) off[base] = excl;
    if (base + 1 < n) off[base + 1] = excl + v0;
    if (base + 2 < n) off[base + 2] = excl + v0 + v1;
    if (base + 3 < n) off[base + 3] = excl + v0 + v1 + v2;
    if (t == 255) bsum[blockIdx.x] = s[255];
}

__global__ __launch_bounds__(256) void scan_bsums(
    int* __restrict__ bsum, int nb, int* __restrict__ off, int n) {
    __shared__ int s[256];
    const int t = threadIdx.x;
    int v = (t < nb) ? bsum[t] : 0;
    s[t] = v;
    __syncthreads();
    for (int step = 1; step < 256; step <<= 1) {
        int q = (t >= step) ? s[t - step] : 0;
        __syncthreads();
        s[t] += q;
        __syncthreads();
    }
    if (t < nb) bsum[t] = s[t] - v;          // exclusive
    if (t == 255) off[n] = s[255];           // grand total
}

__global__ __launch_bounds__(256) void scan_add(
    int* __restrict__ off, const int* __restrict__ bsum, int n) {
    int b = blockIdx.x;
    int add = bsum[b];
    int base = b * 1024;
    int end = base + 1024 < n ? base + 1024 : n;
    for (int i = base + threadIdx.x; i < end; i += 256) off[i] += add;
}

__global__ __launch_bounds__(256) void scatter_all(
    const int* __restrict__ si_lh, const int* __restrict__ di_lh,
    const int* __restrict__ si_hh, const int* __restrict__ di_hh,
    int* __restrict__ cur, int* __restrict__ csr) {
    for (int i = blockIdx.x * blockDim.x + threadIdx.x; i < ETOT;
         i += gridDim.x * blockDim.x) {
        int d, s, bucket;
        if (i < E_LH) {
            d = di_lh[i]; s = si_lh[i]; bucket = d;
        } else {
            int j = i - E_LH;
            if (j < E_HH) { d = di_hh[j]; s = si_hh[j]; }
            else { d = s = j - E_HH; }
            bucket = N_HIGH + d;
        }
        int p = atomicAdd(&cur[bucket], 1);
        csr[p] = s;
    }
}

// ---------- fused GATv2 (bf16 hl/hr, bf16 out): logit+softmax+mean+bias ----
template <int H, int C, bool HR_ONFLY>
__global__ __launch_bounds__(256) void gat_gather(
    const u16* __restrict__ hl, const u16* __restrict__ hr,
    const float* __restrict__ xh, const float* __restrict__ Wr,
    const float* __restrict__ br,
    const int* __restrict__ rowptr, const int* __restrict__ csr_src,
    const float* __restrict__ att, const float* __restrict__ bias,
    u16* __restrict__ out, int outStride, int outOfs, int Ndst,
    const float* __restrict__ col0) {
    constexpr int HC = H * C;
    constexpr int VPL = HC / 64;
    constexpr int LPH = C / VPL;
    using RawT = typename RawTT<VPL>::T;
    int w = blockIdx.x * (blockDim.x >> 6) + (threadIdx.x >> 6);
    if (w >= Ndst) return;
    const int l = threadIdx.x & 63;

    float hrv[VPL], attv[VPL];
    if constexpr (HR_ONFLY) {
        static_assert(!HR_ONFLY || VPL == 4, "onfly assumes VPL==4");
        float xv = xh[w];
        float4 wr = *reinterpret_cast<const float4*>(Wr + l * 4);
        float4 bb = *reinterpret_cast<const float4*>(br + l * 4);
        hrv[0] = fmaf(xv, wr.x, bb.x); hrv[1] = fmaf(xv, wr.y, bb.y);
        hrv[2] = fmaf(xv, wr.z, bb.z); hrv[3] = fmaf(xv, wr.w, bb.w);
        float4 u = *reinterpret_cast<const float4*>(att + l * 4);
        attv[0] = u.x; attv[1] = u.y; attv[2] = u.z; attv[3] = u.w;
    } else if constexpr (VPL == 4) {
        ushort4 t = *(reinterpret_cast<const ushort4*>(hr + (size_t)w * HC) + l);
        hrv[0] = bf2f(t.x); hrv[1] = bf2f(t.y); hrv[2] = bf2f(t.z); hrv[3] = bf2f(t.w);
        float4 u = *reinterpret_cast<const float4*>(att + l * 4);
        attv[0] = u.x; attv[1] = u.y; attv[2] = u.z; attv[3] = u.w;
    } else {
#pragma unroll
        for (int j = 0; j < VPL; j++) {
            hrv[j] = bf2f(hr[(size_t)w * HC + l * VPL + j]);
            attv[j] = att[l * VPL + j];
        }
    }

    const int e0 = rowptr[w], e1 = rowptr[w + 1];
    float m = -3.4e38f, s = 0.f;
    float acc[VPL] = {};

    auto ldraw = [&](int sv) -> RawT {
        if constexpr (VPL == 4)
            return *(reinterpret_cast<const ushort4*>(hl + (size_t)sv * HC) + l);
        else
            return hl[(size_t)sv * HC + l];
    };
    auto proc = [&](RawT t) {
        float hlv[VPL];
        if constexpr (VPL == 4) {
            hlv[0] = bf2f(t.x); hlv[1] = bf2f(t.y);
            hlv[2] = bf2f(t.z); hlv[3] = bf2f(t.w);
        } else {
            hlv[0] = bf2f(t);
        }
        float v = 0.f;
#pragma unroll
        for (int j = 0; j < VPL; j++) {
            float z = hlv[j] + hrv[j];
            v = fmaf(fmaxf(z, 0.2f * z), attv[j], v);
        }
#pragma unroll
        for (int t2 = 1; t2 < LPH; t2 <<= 1) v += __shfl_xor(v, t2, 64);
        float d = v - m;
        bool up = d > 0.f;
        float ef = __expf(-fabsf(d));   // first edge: d=inf -> ef=0
        float sc = up ? ef : 1.f;
        float p  = up ? 1.f : ef;
        m = up ? v : m;
        s = fmaf(s, sc, p);
#pragma unroll
        for (int j = 0; j < VPL; j++) acc[j] = fmaf(acc[j], sc, p * hlv[j]);
    };

    int e = e0;
    for (; e + 3 < e1; e += 4) {
        int sv0 = csr_src[e];
        int sv1 = csr_src[e + 1];
        int sv2 = csr_src[e + 2];
        int sv3 = csr_src[e + 3];
        RawT t0 = ldraw(sv0);
        RawT t1 = ldraw(sv1);
        RawT t2 = ldraw(sv2);
        RawT t3 = ldraw(sv3);
        proc(t0); proc(t1); proc(t2); proc(t3);
    }
    for (; e < e1; e++) {
        RawT t = ldraw(csr_src[e]);
        proc(t);
    }

    float inv = 1.f / (s + 1e-16f);
    float dnorm = inv / fmaxf((float)(e1 - e0), 1.f);
    if constexpr (VPL == 4) {
        if (((outOfs | outStride) & 3) == 0) {
            ushort4 o;
            o.x = (u16)f2bf(acc[0] * dnorm + bias[l * 4 + 0]);
            o.y = (u16)f2bf(acc[1] * dnorm + bias[l * 4 + 1]);
            o.z = (u16)f2bf(acc[2] * dnorm + bias[l * 4 + 2]);
            o.w = (u16)f2bf(acc[3] * dnorm + bias[l * 4 + 3]);
            *(reinterpret_cast<ushort4*>(out + (size_t)w * outStride + outOfs) + l) = o;
        } else {
#pragma unroll
            for (int j = 0; j < 4; j++)
                out[(size_t)w * outStride + outOfs + l * 4 + j] =
                    (u16)f2bf(acc[j] * dnorm + bias[l * 4 + j]);
        }
    } else {
#pragma unroll
        for (int j = 0; j < VPL; j++)
            out[(size_t)w * outStride + outOfs + l * VPL + j] =
                (u16)f2bf(acc[j] * dnorm + bias[l * VPL + j]);
    }
    if (col0 && l == 0) out[(size_t)w * outStride] = (u16)f2bf(col0[w]);
}

// ----------- BN stats stage 1: per-block partial sums, no atomics ----------
// partials[b * 2F + s] (coalesced writes). For F==64, 4 threads/col reduced
// via LDS first.
__global__ __launch_bounds__(256) void bn_partial2(
    const u16* __restrict__ x, int Nrows, int F, float* __restrict__ partials) {
    const int t = threadIdx.x;
    const int b = blockIdx.x;
    if (F == 64) {
        int col = t & 63, rofs = t >> 6;
        float s1 = 0.f, s2 = 0.f;
        for (int r0 = b * 8; r0 < Nrows; r0 += RBLK * 8) {
#pragma unroll
            for (int u = 0; u < 2; u++) {
                int r = r0 + u * 4 + rofs;
                if (r < Nrows) {
                    float v = bf2f(x[(size_t)r * 64 + col]);
                    s1 += v; s2 += v * v;
                }
            }
        }
        __shared__ float l1[256], l2[256];
        l1[t] = s1; l2[t] = s2;
        __syncthreads();
        if (t < 64) {
            s1 = l1[t] + l1[t + 64] + l1[t + 128] + l1[t + 192];
            s2 = l2[t] + l2[t + 64] + l2[t + 128] + l2[t + 192];
            partials[(size_t)b * 128 + t] = s1;
            partials[(size_t)b * 128 + 64 + t] = s2;
        }
    } else {
        const bool extra = (F > 256) && (t < F - 256);
        const int nstat = 2 * F;
        float a1 = 0.f, a2 = 0.f, c1 = 0.f, c2 = 0.f;
        for (int r0 = b * 4; r0 < Nrows; r0 += RBLK * 4) {
#pragma unroll
            for (int u = 0; u < 4; u++) {
                int r = r0 + u;
                if (r < Nrows) {
                    const u16* row = x + (size_t)r * F;
                    float v = bf2f(row[t]);
                    a1 += v; a2 += v * v;
                    if (extra) {
                        float q = bf2f(row[t + 256]);
                        c1 += q; c2 += q * q;
                    }
                }
            }
        }
        partials[(size_t)b * nstat + t] = a1;
        partials[(size_t)b * nstat + F + t] = a2;
        if (extra) {
            partials[(size_t)b * nstat + t + 256] = c1;
            partials[(size_t)b * nstat + F + t + 256] = c2;
        }
    }
}

// ----------- BN stats stage 2: reduce partials -> bsum (no atomics) --------
// 64 stats per block; thread (sl, ch) sums b = ch, ch+4, ... coalesced.
__global__ __launch_bounds__(256) void bn_reduce(
    const float* __restrict__ partials, int nstat, float* __restrict__ bsum) {
    const int sl = threadIdx.x & 63, ch = threadIdx.x >> 6;
    const int s = blockIdx.x * 64 + sl;
    float v = 0.f;
    if (s < nstat) {
        for (int b = ch; b < RBLK; b += 4)
            v += partials[(size_t)b * nstat + s];
    }
    __shared__ float l[256];
    l[threadIdx.x] = v;
    __syncthreads();
    if (ch == 0 && s < nstat)
        bsum[s] = l[sl] + l[sl + 64] + l[sl + 128] + l[sl + 192];
}

// y[i] = dot64(hid[i], W2) + b2
__global__ __launch_bounds__(256) void dot_w2(const float* __restrict__ hid,
                                              const float* __restrict__ W2,
                                              const float* __restrict__ b2,
                                              float* __restrict__ y, int N) {
    int w = blockIdx.x * (blockDim.x >> 6) + (threadIdx.x >> 6);
    int l = threadIdx.x & 63;
    if (w >= N) return;
    float v = hid[(size_t)w * 64 + l] * W2[l];
#pragma unroll
    for (int m = 1; m < 64; m <<= 1) v += __shfl_xor(v, m, 64);
    if (l == 0) y[w] = v + b2[0];
}

// ---------------------------------------------------------------------------
extern "C" void kernel_launch(void* const* d_in, const int* in_sizes, int n_in,
                              void* d_out, int out_size, void* d_ws, size_t ws_size,
                              hipStream_t stream) {
    const float* xl   = (const float*)d_in[0];
    const float* xh   = (const float*)d_in[1];
    const float* zstd = (const float*)d_in[2];
    const int* si_lh  = (const int*)d_in[3];
    const int* di_lh  = (const int*)d_in[4];
    const int* si_hh  = (const int*)d_in[5];
    const int* di_hh  = (const int*)d_in[6];
    int a = 7;
    const float *d_Wl = (const float*)d_in[a++], *d_bl = (const float*)d_in[a++],
                *d_Wr = (const float*)d_in[a++], *d_br = (const float*)d_in[a++],
                *d_att = (const float*)d_in[a++], *d_b = (const float*)d_in[a++];
    const float *p1_Wl = (const float*)d_in[a++], *p1_bl = (const float*)d_in[a++],
                *p1_Wr = (const float*)d_in[a++], *p1_br = (const float*)d_in[a++],
                *p1_att = (const float*)d_in[a++], *p1_b = (const float*)d_in[a++];
    const float *p2_Wl = (const float*)d_in[a++], *p2_bl = (const float*)d_in[a++],
                *p2_Wr = (const float*)d_in[a++], *p2_br = (const float*)d_in[a++],
                *p2_att = (const float*)d_in[a++], *p2_b = (const float*)d_in[a++];
    const float *p3_Wl = (const float*)d_in[a++], *p3_bl = (const float*)d_in[a++],
                *p3_Wr = (const float*)d_in[a++], *p3_br = (const float*)d_in[a++],
                *p3_att = (const float*)d_in[a++], *p3_b = (const float*)d_in[a++];
    const float *bn0_g = (const float*)d_in[a++], *bn0_b = (const float*)d_in[a++],
                *bn1_g = (const float*)d_in[a++], *bn1_b = (const float*)d_in[a++],
                *bn2_g = (const float*)d_in[a++], *bn2_b = (const float*)d_in[a++],
                *bn3_g = (const float*)d_in[a++], *bn3_b = (const float*)d_in[a++];
    const float *pr_W1 = (const float*)d_in[a++], *pr_b1 = (const float*)d_in[a++],
                *pr_W2 = (const float*)d_in[a++], *pr_b2 = (const float*)d_in[a++];
    float* y = (float*)d_out;

    const int N = N_HIGH;
    const int NMT = 3125;                    // 50000/16
    const int NB2 = (2 * N + 1023) / 1024;   // scan blocks over 2N = 98
    // ---- workspace layout (regions sized as before; x buffers hold bf16) ---
    float* ws = (float*)d_ws;
    float* xA = ws;                           // region 50000*257 f32 (bf16 used / hosts AfA)
    float* xB = xA + (size_t)N * 257;         // region 50000*256 f32 (bf16 used / hosts AfB)
    float* hl = xB + (size_t)N * 256;         // 50000*256 (bf16 used)
    float* hr = hl + (size_t)N * 256;         // 50000*256 (bf16 used; dead during BN -> partials)
    bf16x8* xl_f = (bf16x8*)(hr + (size_t)N * 256);   // 320*4*64 frags
    bf16x8* wf_d   = xl_f + 320 * 4 * 64;     // 16*4*64
    bf16x8* wf_p1l = wf_d + 16 * 4 * 64;      // 16*9*64
    bf16x8* wf_p1r = wf_p1l + 16 * 9 * 64;
    bf16x8* wf_p2l = wf_p1r + 16 * 9 * 64;    // 16*8*64
    bf16x8* wf_p2r = wf_p2l + 16 * 8 * 64;
    bf16x8* wf_p3l = wf_p2r + 16 * 8 * 64;    // 4*8*64
    bf16x8* wf_p3r = wf_p3l + 4 * 8 * 64;
    bf16x8* wf_pr1 = wf_p3r + 4 * 8 * 64;     // 4*2*64
    float* bsum = (float*)(wf_pr1 + 4 * 2 * 64); // 514 (sum | sumsq)
    int* bscan  = (int*)(bsum + 514);         // 256 (scan block sums)
    int* cnt    = bscan + 256;                // 2N  (lh | hh histograms)
    int* off    = cnt + 2 * N;                // 2N+1 (combined rowptrs)
    int* cur    = off + 2 * N + 1;            // 2N  (scatter cursors)
    int* csr    = cur + 2 * N;                // 650000 (combined)
    size_t need = (size_t)((char*)(csr + ETOT) - (char*)ws);
    if (ws_size < need) return;
    bf16x8* AfB = (bf16x8*)xB;   // A-frags overlaying xB region (while dead)
    bf16x8* AfA = (bf16x8*)xA;   // A-frags overlaying xA region (while dead)
    u16* xA16 = (u16*)xA;
    u16* xB16 = (u16*)xB;
    u16* hl16 = (u16*)hl;
    u16* hr16 = (u16*)hr;
    float* partials = hr;        // overlay: hr region is dead during BN stats
    int* rp_lh = off;            // rowptr for lh  (off[N] == E_LH boundary)
    int* rp_hh = off + N;        // rowptr for hh  (absolute into csr)

    dim3 blk(256);
    auto wgrid = [](int E) { return dim3((E + 3) / 4); };
    auto egrid = [](size_t total) {
        size_t g = (total + 255) / 256;
        return dim3((unsigned)(g > 2048 ? 2048 : g));
    };
    auto bn_run = [&](const u16* x, int F) {
        bn_partial2<<<dim3(RBLK), blk, 0, stream>>>(x, N, F, partials);
        bn_reduce<<<dim3((2 * F + 63) / 64), blk, 0, stream>>>(partials, 2 * F, bsum);
    };

    // ===================== weight fragment transforms (one kernel) ==========
    WtJobs jobs;
    jobs.W[0] = d_Wl;  jobs.out[0] = wf_d;   jobs.K[0] = 125; jobs.Nn[0] = 256; jobs.nnt[0] = 16; jobs.nkt[0] = 4;
    jobs.W[1] = p1_Wl; jobs.out[1] = wf_p1l; jobs.K[1] = 257; jobs.Nn[1] = 256; jobs.nnt[1] = 16; jobs.nkt[1] = 9;
    jobs.W[2] = p1_Wr; jobs.out[2] = wf_p1r; jobs.K[2] = 257; jobs.Nn[2] = 256; jobs.nnt[2] = 16; jobs.nkt[2] = 9;
    jobs.W[3] = p2_Wl; jobs.out[3] = wf_p2l; jobs.K[3] = 256; jobs.Nn[3] = 256; jobs.nnt[3] = 16; jobs.nkt[3] = 8;
    jobs.W[4] = p2_Wr; jobs.out[4] = wf_p2r; jobs.K[4] = 256; jobs.Nn[4] = 256; jobs.nnt[4] = 16; jobs.nkt[4] = 8;
    jobs.W[5] = p3_Wl; jobs.out[5] = wf_p3l; jobs.K[5] = 256; jobs.Nn[5] = 64;  jobs.nnt[5] = 4;  jobs.nkt[5] = 8;
    jobs.W[6] = p3_Wr; jobs.out[6] = wf_p3r; jobs.K[6] = 256; jobs.Nn[6] = 64;  jobs.nnt[6] = 4;  jobs.nkt[6] = 8;
    jobs.W[7] = pr_W1; jobs.out[7] = wf_pr1; jobs.K[7] = 64;  jobs.Nn[7] = 64;  jobs.nnt[7] = 4;  jobs.nkt[7] = 2;
    wt_frag_all<<<dim3(36, 8), blk, 0, stream>>>(jobs);
    cast_frag<<<dim3(320), blk, 0, stream>>>(xl, N_LOW, 125, xl_f, 320, 4);

    // ===================== combined CSR build ===============================
    hipMemsetAsync(cnt, 0, 2 * (size_t)N * sizeof(int), stream);
    hist_all<<<egrid(ETOT), blk, 0, stream>>>(di_lh, di_hh, cnt);
    scan_partial<<<dim3(NB2), blk, 0, stream>>>(cnt, off, bscan, 2 * N);
    scan_bsums<<<dim3(1), blk, 0, stream>>>(bscan, NB2, off, 2 * N);
    scan_add<<<dim3(NB2), blk, 0, stream>>>(off, bscan, 2 * N);
    hipMemcpyAsync(cur, off, 2 * (size_t)N * sizeof(int), hipMemcpyDeviceToDevice, stream);
    scatter_all<<<egrid(ETOT), blk, 0, stream>>>(si_lh, di_lh, si_hh, di_hh, cur, csr);

    // ===================== d layer (low -> high, H=1, C=256) ================
    gemm_mfma<false, true><<<dim3(4, 40), blk, 0, stream>>>(xl_f, wf_d, d_bl, hl, N_LOW, 256, 4);
    gat_gather<1, 256, true><<<wgrid(N), blk, 0, stream>>>(
        hl16, nullptr, xh, d_Wr, d_br, rp_lh, csr, d_att, d_b, xA16, 257, 1, N, zstd);

    // ===================== bn0 + frag cast ==================================
    bn_run(xA16, 257);
    bn_frag<false><<<dim3(2048), blk, 0, stream>>>(xA16, N, 257, bsum, bn0_g, bn0_b, AfB, NMT, 9);

    // ===================== p1 (H=4, C=64) ===================================
    gemm_mfma2<<<dim3(4, 391, 2), blk, 0, stream>>>(AfB, wf_p1l, wf_p1r, p1_bl, p1_br, hl, hr, N, 256, 9);
    gat_gather<4, 64, false><<<wgrid(N), blk, 0, stream>>>(
        hl16, hr16, nullptr, nullptr, nullptr, rp_hh, csr, p1_att, p1_b, xB16, 256, 0, N, nullptr);
    bn_run(xB16, 256);
    bn_frag<true><<<dim3(2048), blk, 0, stream>>>(xB16, N, 256, bsum, bn1_g, bn1_b, AfA, NMT, 8);

    // ===================== p2 (H=4, C=64) ===================================
    gemm_mfma2<<<dim3(4, 391, 2), blk, 0, stream>>>(AfA, wf_p2l, wf_p2r, p2_bl, p2_br, hl, hr, N, 256, 8);
    gat_gather<4, 64, false><<<wgrid(N), blk, 0, stream>>>(
        hl16, hr16, nullptr, nullptr, nullptr, rp_hh, csr, p2_att, p2_b, xA16, 256, 0, N, nullptr);
    bn_run(xA16, 256);
    bn_frag<true><<<dim3(2048), blk, 0, stream>>>(xA16, N, 256, bsum, bn2_g, bn2_b, AfB, NMT, 8);

    // ===================== p3 (H=1, C=64) ===================================
    gemm_mfma2<<<dim3(1, 391, 2), blk, 0, stream>>>(AfB, wf_p3l, wf_p3r, p3_bl, p3_br, hl, hr, N, 64, 8);
    gat_gather<1, 64, false><<<wgrid(N), blk, 0, stream>>>(
        hl16, hr16, nullptr, nullptr, nullptr, rp_hh, csr, p3_att, p3_b, xB16, 64, 0, N, nullptr);
    bn_run(xB16, 64);
    bn_frag<true><<<dim3(2048), blk, 0, stream>>>(xB16, N, 64, bsum, bn3_g, bn3_b, AfA, NMT, 2);

    // ===================== predictor MLP ====================================
    gemm_mfma<true, false><<<dim3(1, 391), blk, 0, stream>>>(AfA, wf_pr1, pr_b1, hl, N, 64, 2);
    dot_w2<<<wgrid(N), blk, 0, stream>>>(hl, pr_W2, pr_b2, y, N);
}

// Round 13
// 531.069 us; speedup vs baseline: 1.9910x; 1.9910x over previous
//
#include <hip/hip_runtime.h>
#include <math.h>

#define DEV __device__ __forceinline__

static const int N_LOW = 5000, N_HIGH = 50000, E_LH = 200000, E_HH = 400000;
static const int E2 = E_HH + N_HIGH;   // 450000 with self loops
static const int ETOT = E_LH + E2;     // 650000 combined
static const int RBLK = 2048;          // bn stage-1 blocks

typedef __attribute__((ext_vector_type(8))) short bf16x8;
typedef __attribute__((ext_vector_type(4))) float f32x4;
typedef __attribute__((ext_vector_type(8))) unsigned short u16x8;
typedef unsigned short u16;

DEV short f2bf(float v) {            // round-to-nearest-even f32 -> bf16
    unsigned u = __float_as_uint(v);
    u += 0x7FFFu + ((u >> 16) & 1u);
    return (short)(u >> 16);
}
DEV float bf2f(u16 u) { return __uint_as_float(((unsigned)u) << 16); }

template <int VPL> struct RawTT { using T = u16; };
template <> struct RawTT<4> { using T = ushort4; };

// =================== MFMA GEMM on fragment-ordered operands =================
template <bool RELU, bool BF16OUT>
DEV void gemm_body(const bf16x8* __restrict__ Af, const bf16x8* __restrict__ Bf,
                   const float* __restrict__ bias, float* __restrict__ C,
                   int M, int N, int nkt) {
    const int l = threadIdx.x & 63;
    const int w = threadIdx.x >> 6;
    const int nt0 = blockIdx.x * 4;
    const int mt0 = blockIdx.y * 8 + w * 2;
    f32x4 acc[2][4];
#pragma unroll
    for (int i = 0; i < 2; i++)
#pragma unroll
        for (int j = 0; j < 4; j++) acc[i][j] = (f32x4){0.f, 0.f, 0.f, 0.f};
    const bf16x8* a0p = Af + (size_t)mt0 * nkt * 64 + l;
    const bf16x8* a1p = a0p + (size_t)nkt * 64;
    const bf16x8* bp = Bf + (size_t)nt0 * nkt * 64 + l;
    for (int kt = 0; kt < nkt; kt++) {
        bf16x8 a0 = a0p[kt * 64];
        bf16x8 a1 = a1p[kt * 64];
        bf16x8 b0 = bp[kt * 64];
        bf16x8 b1 = bp[(size_t)(nkt + kt) * 64];
        bf16x8 b2 = bp[(size_t)(2 * nkt + kt) * 64];
        bf16x8 b3 = bp[(size_t)(3 * nkt + kt) * 64];
        acc[0][0] = __builtin_amdgcn_mfma_f32_16x16x32_bf16(a0, b0, acc[0][0], 0, 0, 0);
        acc[0][1] = __builtin_amdgcn_mfma_f32_16x16x32_bf16(a0, b1, acc[0][1], 0, 0, 0);
        acc[0][2] = __builtin_amdgcn_mfma_f32_16x16x32_bf16(a0, b2, acc[0][2], 0, 0, 0);
        acc[0][3] = __builtin_amdgcn_mfma_f32_16x16x32_bf16(a0, b3, acc[0][3], 0, 0, 0);
        acc[1][0] = __builtin_amdgcn_mfma_f32_16x16x32_bf16(a1, b0, acc[1][0], 0, 0, 0);
        acc[1][1] = __builtin_amdgcn_mfma_f32_16x16x32_bf16(a1, b1, acc[1][1], 0, 0, 0);
        acc[1][2] = __builtin_amdgcn_mfma_f32_16x16x32_bf16(a1, b2, acc[1][2], 0, 0, 0);
        acc[1][3] = __builtin_amdgcn_mfma_f32_16x16x32_bf16(a1, b3, acc[1][3], 0, 0, 0);
    }
    const int colb = nt0 * 16 + (l & 15);
    const int rsub = (l >> 4) * 4;
#pragma unroll
    for (int mi = 0; mi < 2; mi++) {
        int rowb = (mt0 + mi) * 16 + rsub;
#pragma unroll
        for (int r = 0; r < 4; r++) {
            int row = rowb + r;
            if (row >= M) continue;
#pragma unroll
            for (int n = 0; n < 4; n++) {
                int col = colb + n * 16;
                float v = acc[mi][n][r] + bias[col];
                if (RELU) v = fmaxf(v, 0.f);
                if (BF16OUT)
                    ((u16*)C)[(size_t)row * N + col] = (u16)f2bf(v);
                else
                    C[(size_t)row * N + col] = v;
            }
        }
    }
}

template <bool RELU, bool BF16OUT>
__global__ __launch_bounds__(256) void gemm_mfma(
    const bf16x8* __restrict__ Af, const bf16x8* __restrict__ Bf,
    const float* __restrict__ bias, float* __restrict__ C,
    int M, int N, int nkt) {
    gemm_body<RELU, BF16OUT>(Af, Bf, bias, C, M, N, nkt);
}

// paired variant: blockIdx.z selects (Bf0,bias0,C0) or (Bf1,bias1,C1); same A.
__global__ __launch_bounds__(256) void gemm_mfma2(
    const bf16x8* __restrict__ Af,
    const bf16x8* __restrict__ Bf0, const bf16x8* __restrict__ Bf1,
    const float* __restrict__ bias0, const float* __restrict__ bias1,
    float* __restrict__ C0, float* __restrict__ C1,
    int M, int N, int nkt) {
    if (blockIdx.z == 0)
        gemm_body<false, true>(Af, Bf0, bias0, C0, M, N, nkt);
    else
        gemm_body<false, true>(Af, Bf1, bias1, C1, M, N, nkt);
}

// --------- BN-apply (stats from raw sums) + (relu) + bf16 frag cast --------
// x has row stride STR (u16 elems); sums layout [SS sums][SS sumsqs].
template <bool RELU>
__global__ __launch_bounds__(256) void bn_frag(
    const u16* __restrict__ x, int Nrows, int F, int STR, int SS,
    const float* __restrict__ sums,
    const float* __restrict__ g, const float* __restrict__ b,
    bf16x8* __restrict__ Af, int nmt, int nkt) {
    int total = nmt * nkt * 64;
    for (int idx = blockIdx.x * blockDim.x + threadIdx.x; idx < total;
         idx += gridDim.x * blockDim.x) {
        int mt = idx / (nkt * 64);
        int rem = idx - mt * (nkt * 64);
        int kt = rem >> 6, l = rem & 63;
        int row = mt * 16 + (l & 15);
        int colb = kt * 32 + (l >> 4) * 8;
        bf16x8 o;
#pragma unroll
        for (int j = 0; j < 8; j++) {
            int col = colb + j;
            float v = 0.f;
            if (row < Nrows && col < F) {
                float mu = sums[col] / Nrows;
                float var = sums[SS + col] / Nrows - mu * mu;
                float istd = rsqrtf(fmaxf(var, 0.f) + 1e-5f);
                v = (bf2f(x[(size_t)row * STR + col]) - mu) * istd * g[col] + b[col];
                if (RELU) v = fmaxf(v, 0.f);
            }
            o[j] = f2bf(v);
        }
        Af[idx] = o;
    }
}

// --------- plain cast (xl f32) into fragment-ordered A, zero-padded --------
__global__ __launch_bounds__(256) void cast_frag(
    const float* __restrict__ x, int Nrows, int F,
    bf16x8* __restrict__ Af, int nmt, int nkt) {
    int total = nmt * nkt * 64;
    for (int idx = blockIdx.x * blockDim.x + threadIdx.x; idx < total;
         idx += gridDim.x * blockDim.x) {
        int mt = idx / (nkt * 64);
        int rem = idx - mt * (nkt * 64);
        int kt = rem >> 6, l = rem & 63;
        int row = mt * 16 + (l & 15);
        int colb = kt * 32 + (l >> 4) * 8;
        bf16x8 o;
#pragma unroll
        for (int j = 0; j < 8; j++) {
            int col = colb + j;
            o[j] = (row < Nrows && col < F) ? f2bf(x[(size_t)row * F + col]) : (short)0;
        }
        Af[idx] = o;
    }
}

// --------- ALL weight [K][N] -> fragment-ordered B transforms in one -------
struct WtJobs {
    const float* W[8];
    bf16x8* out[8];
    int K[8], Nn[8], nnt[8], nkt[8];
};
__global__ __launch_bounds__(256) void wt_frag_all(WtJobs jobs) {
    const int job = blockIdx.y;
    const float* W = jobs.W[job];
    bf16x8* Bf = jobs.out[job];
    const int K = jobs.K[job], N = jobs.Nn[job];
    const int nkt = jobs.nkt[job];
    int total = jobs.nnt[job] * nkt * 64;
    for (int idx = blockIdx.x * blockDim.x + threadIdx.x; idx < total;
         idx += gridDim.x * blockDim.x) {
        int nt = idx / (nkt * 64);
        int rem = idx - nt * (nkt * 64);
        int kt = rem >> 6, l = rem & 63;
        int col = nt * 16 + (l & 15);
        int kb = kt * 32 + (l >> 4) * 8;
        bf16x8 o;
#pragma unroll
        for (int j = 0; j < 8; j++) {
            int k = kb + j;
            o[j] = (k < K && col < N) ? f2bf(W[(size_t)k * N + col]) : (short)0;
        }
        Bf[idx] = o;
    }
}

// ------------- combined CSR build over BOTH edge sets ----------------------
__global__ __launch_bounds__(256) void hist_all(
    const int* __restrict__ di_lh, const int* __restrict__ di_hh,
    int* __restrict__ cnt) {
    for (int i = blockIdx.x * blockDim.x + threadIdx.x; i < ETOT;
         i += gridDim.x * blockDim.x) {
        if (i < E_LH) {
            atomicAdd(&cnt[di_lh[i]], 1);
        } else {
            int j = i - E_LH;
            int d = (j < E_HH) ? di_hh[j] : (j - E_HH);
            atomicAdd(&cnt[N_HIGH + d], 1);
        }
    }
}

// ---- parallel exclusive scan over n ints (3 kernels, chunks of 1024) -------
__global__ __launch_bounds__(256) void scan_partial(
    const int* __restrict__ cnt, int* __restrict__ off,
    int* __restrict__ bsum, int n) {
    __shared__ int s[256];
    const int t = threadIdx.x;
    const int base = blockIdx.x * 1024 + t * 4;
    int v0 = (base < n) ? cnt[base] : 0;
    int v1 = (base + 1 < n) ? cnt[base + 1] : 0;
    int v2 = (base + 2 < n) ? cnt[base + 2] : 0;
    int v3 = (base + 3 < n) ? cnt[base + 3] : 0;
    int tsum = v0 + v1 + v2 + v3;
    s[t] = tsum;
    __syncthreads();
    for (int step = 1; step < 256; step <<= 1) {
        int q = (t >= step) ? s[t - step] : 0;
        __syncthreads();
        s[t] += q;
        __syncthreads();
    }
    int excl = s[t] - tsum;
    if (base < n) off[base] = excl;
    if (base + 1 < n) off[base + 1] = excl + v0;
    if (base + 2 < n) off[base + 2] = excl + v0 + v1;
    if (base + 3 < n) off[base + 3] = excl + v0 + v1 + v2;
    if (t == 255) bsum[blockIdx.x] = s[255];
}

__global__ __launch_bounds__(256) void scan_bsums(
    int* __restrict__ bsum, int nb, int* __restrict__ off, int n) {
    __shared__ int s[256];
    const int t = threadIdx.x;
    int v = (t < nb) ? bsum[t] : 0;
    s[t] = v;
    __syncthreads();
    for (int step = 1; step < 256; step <<= 1) {
        int q = (t >= step) ? s[t - step] : 0;
        __syncthreads();
        s[t] += q;
        __syncthreads();
    }
    if (t < nb) bsum[t] = s[t] - v;          // exclusive
    if (t == 255) off[n] = s[255];           // grand total
}

__global__ __launch_bounds__(256) void scan_add(
    int* __restrict__ off, const int* __restrict__ bsum, int n) {
    int b = blockIdx.x;
    int add = bsum[b];
    int base = b * 1024;
    int end = base + 1024 < n ? base + 1024 : n;
    for (int i = base + threadIdx.x; i < end; i += 256) off[i] += add;
}

__global__ __launch_bounds__(256) void scatter_all(
    const int* __restrict__ si_lh, const int* __restrict__ di_lh,
    const int* __restrict__ si_hh, const int* __restrict__ di_hh,
    int* __restrict__ cur, int* __restrict__ csr) {
    for (int i = blockIdx.x * blockDim.x + threadIdx.x; i < ETOT;
         i += gridDim.x * blockDim.x) {
        int d, s, bucket;
        if (i < E_LH) {
            d = di_lh[i]; s = si_lh[i]; bucket = d;
        } else {
            int j = i - E_LH;
            if (j < E_HH) { d = di_hh[j]; s = si_hh[j]; }
            else { d = s = j - E_HH; }
            bucket = N_HIGH + d;
        }
        int p = atomicAdd(&cur[bucket], 1);
        csr[p] = s;
    }
}

// ---------- fused GATv2 (bf16 hl/hr, bf16 out): logit+softmax+mean+bias ----
template <int H, int C, bool HR_ONFLY>
__global__ __launch_bounds__(256) void gat_gather(
    const u16* __restrict__ hl, const u16* __restrict__ hr,
    const float* __restrict__ xh, const float* __restrict__ Wr,
    const float* __restrict__ br,
    const int* __restrict__ rowptr, const int* __restrict__ csr_src,
    const float* __restrict__ att, const float* __restrict__ bias,
    u16* __restrict__ out, int outStride, int outOfs, int Ndst,
    const float* __restrict__ col0) {
    constexpr int HC = H * C;
    constexpr int VPL = HC / 64;
    constexpr int LPH = C / VPL;
    using RawT = typename RawTT<VPL>::T;
    int w = blockIdx.x * (blockDim.x >> 6) + (threadIdx.x >> 6);
    if (w >= Ndst) return;
    const int l = threadIdx.x & 63;

    float hrv[VPL], attv[VPL];
    if constexpr (HR_ONFLY) {
        static_assert(!HR_ONFLY || VPL == 4, "onfly assumes VPL==4");
        float xv = xh[w];
        float4 wr = *reinterpret_cast<const float4*>(Wr + l * 4);
        float4 bb = *reinterpret_cast<const float4*>(br + l * 4);
        hrv[0] = fmaf(xv, wr.x, bb.x); hrv[1] = fmaf(xv, wr.y, bb.y);
        hrv[2] = fmaf(xv, wr.z, bb.z); hrv[3] = fmaf(xv, wr.w, bb.w);
        float4 u = *reinterpret_cast<const float4*>(att + l * 4);
        attv[0] = u.x; attv[1] = u.y; attv[2] = u.z; attv[3] = u.w;
    } else if constexpr (VPL == 4) {
        ushort4 t = *(reinterpret_cast<const ushort4*>(hr + (size_t)w * HC) + l);
        hrv[0] = bf2f(t.x); hrv[1] = bf2f(t.y); hrv[2] = bf2f(t.z); hrv[3] = bf2f(t.w);
        float4 u = *reinterpret_cast<const float4*>(att + l * 4);
        attv[0] = u.x; attv[1] = u.y; attv[2] = u.z; attv[3] = u.w;
    } else {
#pragma unroll
        for (int j = 0; j < VPL; j++) {
            hrv[j] = bf2f(hr[(size_t)w * HC + l * VPL + j]);
            attv[j] = att[l * VPL + j];
        }
    }

    const int e0 = rowptr[w], e1 = rowptr[w + 1];
    float m = -3.4e38f, s = 0.f;
    float acc[VPL] = {};

    auto ldraw = [&](int sv) -> RawT {
        if constexpr (VPL == 4)
            return *(reinterpret_cast<const ushort4*>(hl + (size_t)sv * HC) + l);
        else
            return hl[(size_t)sv * HC + l];
    };
    auto proc = [&](RawT t) {
        float hlv[VPL];
        if constexpr (VPL == 4) {
            hlv[0] = bf2f(t.x); hlv[1] = bf2f(t.y);
            hlv[2] = bf2f(t.z); hlv[3] = bf2f(t.w);
        } else {
            hlv[0] = bf2f(t);
        }
        float v = 0.f;
#pragma unroll
        for (int j = 0; j < VPL; j++) {
            float z = hlv[j] + hrv[j];
            v = fmaf(fmaxf(z, 0.2f * z), attv[j], v);
        }
#pragma unroll
        for (int t2 = 1; t2 < LPH; t2 <<= 1) v += __shfl_xor(v, t2, 64);
        float d = v - m;
        bool up = d > 0.f;
        float ef = __expf(-fabsf(d));   // first edge: d=inf -> ef=0
        float sc = up ? ef : 1.f;
        float p  = up ? 1.f : ef;
        m = up ? v : m;
        s = fmaf(s, sc, p);
#pragma unroll
        for (int j = 0; j < VPL; j++) acc[j] = fmaf(acc[j], sc, p * hlv[j]);
    };

    int e = e0;
    for (; e + 3 < e1; e += 4) {
        int sv0 = csr_src[e];
        int sv1 = csr_src[e + 1];
        int sv2 = csr_src[e + 2];
        int sv3 = csr_src[e + 3];
        RawT t0 = ldraw(sv0);
        RawT t1 = ldraw(sv1);
        RawT t2 = ldraw(sv2);
        RawT t3 = ldraw(sv3);
        proc(t0); proc(t1); proc(t2); proc(t3);
    }
    for (; e < e1; e++) {
        RawT t = ldraw(csr_src[e]);
        proc(t);
    }

    float inv = 1.f / (s + 1e-16f);
    float dnorm = inv / fmaxf((float)(e1 - e0), 1.f);
    if constexpr (VPL == 4) {
        if (((outOfs | outStride) & 3) == 0) {
            ushort4 o;
            o.x = (u16)f2bf(acc[0] * dnorm + bias[l * 4 + 0]);
            o.y = (u16)f2bf(acc[1] * dnorm + bias[l * 4 + 1]);
            o.z = (u16)f2bf(acc[2] * dnorm + bias[l * 4 + 2]);
            o.w = (u16)f2bf(acc[3] * dnorm + bias[l * 4 + 3]);
            *(reinterpret_cast<ushort4*>(out + (size_t)w * outStride + outOfs) + l) = o;
        } else {
#pragma unroll
            for (int j = 0; j < 4; j++)
                out[(size_t)w * outStride + outOfs + l * 4 + j] =
                    (u16)f2bf(acc[j] * dnorm + bias[l * 4 + j]);
        }
    } else {
#pragma unroll
        for (int j = 0; j < VPL; j++)
            out[(size_t)w * outStride + outOfs + l * VPL + j] =
                (u16)f2bf(acc[j] * dnorm + bias[l * VPL + j]);
    }
    if (col0 && l == 0) out[(size_t)w * outStride] = (u16)f2bf(col0[w]);
}

// ----------- BN stats stage 1: ushort8 loads, LDS reduce, no atomics -------
// x rows have stride NC*8 u16 (16B-aligned). Block writes 2*NC*8 partials.
template <int NC, int RPB>
__global__ __launch_bounds__(256) void bn_partial3(
    const u16* __restrict__ x, int Nrows, float* __restrict__ partials) {
    constexpr int STR = NC * 8;
    constexpr int NSTAT = 2 * NC * 8;
    const int t = threadIdx.x;
    const int b = blockIdx.x;
    __shared__ float l1[NC * RPB * 8];
    __shared__ float l2[NC * RPB * 8];
    float s1[8] = {}, s2[8] = {};
    if (t < NC * RPB) {
        const int rg = t / NC, cg = t - (t / NC) * NC;
        for (int r = b * RPB + rg; r < Nrows; r += RBLK * RPB) {
            u16x8 p = *reinterpret_cast<const u16x8*>(x + (size_t)r * STR + cg * 8);
#pragma unroll
            for (int j = 0; j < 8; j++) {
                float v = bf2f(p[j]);
                s1[j] += v; s2[j] += v * v;
            }
        }
#pragma unroll
        for (int j = 0; j < 8; j++) {
            l1[t * 8 + j] = s1[j];
            l2[t * 8 + j] = s2[j];
        }
    }
    __syncthreads();
    if (t < NC) {
        float a[8] = {}, c[8] = {};
#pragma unroll
        for (int rg = 0; rg < RPB; rg++)
#pragma unroll
            for (int j = 0; j < 8; j++) {
                a[j] += l1[(rg * NC + t) * 8 + j];
                c[j] += l2[(rg * NC + t) * 8 + j];
            }
#pragma unroll
        for (int j = 0; j < 8; j++) {
            partials[(size_t)b * NSTAT + t * 8 + j] = a[j];
            partials[(size_t)b * NSTAT + NC * 8 + t * 8 + j] = c[j];
        }
    }
}

// ----------- BN stats stage 2: 2D grid, coalesced, few atomics -------------
// grid: x = ceil(nstat/64), y = 32 b-chunks of RBLK/32 = 64 blocks each.
__global__ __launch_bounds__(256) void bn_reduce2(
    const float* __restrict__ partials, int nstat, float* __restrict__ bsum) {
    const int sl = threadIdx.x & 63, ch = threadIdx.x >> 6;
    const int s = blockIdx.x * 64 + sl;
    const int b0 = blockIdx.y * (RBLK / 32);
    float v = 0.f;
    if (s < nstat) {
        for (int b = b0 + ch; b < b0 + RBLK / 32; b += 4)
            v += partials[(size_t)b * nstat + s];
    }
    __shared__ float l[256];
    l[threadIdx.x] = v;
    __syncthreads();
    if (ch == 0 && s < nstat)
        atomicAdd(&bsum[s], l[sl] + l[sl + 64] + l[sl + 128] + l[sl + 192]);
}

// y[i] = dot64(hid[i], W2) + b2
__global__ __launch_bounds__(256) void dot_w2(const float* __restrict__ hid,
                                              const float* __restrict__ W2,
                                              const float* __restrict__ b2,
                                              float* __restrict__ y, int N) {
    int w = blockIdx.x * (blockDim.x >> 6) + (threadIdx.x >> 6);
    int l = threadIdx.x & 63;
    if (w >= N) return;
    float v = hid[(size_t)w * 64 + l] * W2[l];
#pragma unroll
    for (int m = 1; m < 64; m <<= 1) v += __shfl_xor(v, m, 64);
    if (l == 0) y[w] = v + b2[0];
}

// ---------------------------------------------------------------------------
extern "C" void kernel_launch(void* const* d_in, const int* in_sizes, int n_in,
                              void* d_out, int out_size, void* d_ws, size_t ws_size,
                              hipStream_t stream) {
    const float* xl   = (const float*)d_in[0];
    const float* xh   = (const float*)d_in[1];
    const float* zstd = (const float*)d_in[2];
    const int* si_lh  = (const int*)d_in[3];
    const int* di_lh  = (const int*)d_in[4];
    const int* si_hh  = (const int*)d_in[5];
    const int* di_hh  = (const int*)d_in[6];
    int a = 7;
    const float *d_Wl = (const float*)d_in[a++], *d_bl = (const float*)d_in[a++],
                *d_Wr = (const float*)d_in[a++], *d_br = (const float*)d_in[a++],
                *d_att = (const float*)d_in[a++], *d_b = (const float*)d_in[a++];
    const float *p1_Wl = (const float*)d_in[a++], *p1_bl = (const float*)d_in[a++],
                *p1_Wr = (const float*)d_in[a++], *p1_br = (const float*)d_in[a++],
                *p1_att = (const float*)d_in[a++], *p1_b = (const float*)d_in[a++];
    const float *p2_Wl = (const float*)d_in[a++], *p2_bl = (const float*)d_in[a++],
                *p2_Wr = (const float*)d_in[a++], *p2_br = (const float*)d_in[a++],
                *p2_att = (const float*)d_in[a++], *p2_b = (const float*)d_in[a++];
    const float *p3_Wl = (const float*)d_in[a++], *p3_bl = (const float*)d_in[a++],
                *p3_Wr = (const float*)d_in[a++], *p3_br = (const float*)d_in[a++],
                *p3_att = (const float*)d_in[a++], *p3_b = (const float*)d_in[a++];
    const float *bn0_g = (const float*)d_in[a++], *bn0_b = (const float*)d_in[a++],
                *bn1_g = (const float*)d_in[a++], *bn1_b = (const float*)d_in[a++],
                *bn2_g = (const float*)d_in[a++], *bn2_b = (const float*)d_in[a++],
                *bn3_g = (const float*)d_in[a++], *bn3_b = (const float*)d_in[a++];
    const float *pr_W1 = (const float*)d_in[a++], *pr_b1 = (const float*)d_in[a++],
                *pr_W2 = (const float*)d_in[a++], *pr_b2 = (const float*)d_in[a++];
    float* y = (float*)d_out;

    const int N = N_HIGH;
    const int NMT = 3125;                    // 50000/16
    const int NB2 = (2 * N + 1023) / 1024;   // scan blocks over 2N = 98
    // ---- workspace layout (regions sized as before; x buffers hold bf16) ---
    float* ws = (float*)d_ws;
    float* xA = ws;                           // region 50000*257 f32 (bf16 stride-264 used / hosts AfA)
    float* xB = xA + (size_t)N * 257;         // region 50000*256 f32 (bf16 used / hosts AfB)
    float* hl = xB + (size_t)N * 256;         // 50000*256 (bf16 used)
    float* hr = hl + (size_t)N * 256;         // 50000*256 (bf16 used; dead during BN -> partials)
    bf16x8* xl_f = (bf16x8*)(hr + (size_t)N * 256);   // 320*4*64 frags
    bf16x8* wf_d   = xl_f + 320 * 4 * 64;     // 16*4*64
    bf16x8* wf_p1l = wf_d + 16 * 4 * 64;      // 16*9*64
    bf16x8* wf_p1r = wf_p1l + 16 * 9 * 64;
    bf16x8* wf_p2l = wf_p1r + 16 * 9 * 64;    // 16*8*64
    bf16x8* wf_p2r = wf_p2l + 16 * 8 * 64;
    bf16x8* wf_p3l = wf_p2r + 16 * 8 * 64;    // 4*8*64
    bf16x8* wf_p3r = wf_p3l + 4 * 8 * 64;
    bf16x8* wf_pr1 = wf_p3r + 4 * 8 * 64;     // 4*2*64
    float* bsum = (float*)(wf_pr1 + 4 * 2 * 64); // 544 (sum | sumsq, max 2*264)
    int* bscan  = (int*)(bsum + 544);         // 256 (scan block sums)
    int* cnt    = bscan + 256;                // 2N  (lh | hh histograms)
    int* off    = cnt + 2 * N;                // 2N+1 (combined rowptrs)
    int* cur    = off + 2 * N + 1;            // 2N  (scatter cursors)
    int* csr    = cur + 2 * N;                // 650000 (combined)
    size_t need = (size_t)((char*)(csr + ETOT) - (char*)ws);
    if (ws_size < need) return;
    bf16x8* AfB = (bf16x8*)xB;   // A-frags overlaying xB region (while dead)
    bf16x8* AfA = (bf16x8*)xA;   // A-frags overlaying xA region (while dead)
    u16* xA16 = (u16*)xA;        // stride-264 bf16 rows (26.4 MB < region)
    u16* xB16 = (u16*)xB;
    u16* hl16 = (u16*)hl;
    u16* hr16 = (u16*)hr;
    float* partials = hr;        // overlay: hr region is dead during BN stats
    int* rp_lh = off;            // rowptr for lh  (off[N] == E_LH boundary)
    int* rp_hh = off + N;        // rowptr for hh  (absolute into csr)

    dim3 blk(256);
    auto wgrid = [](int E) { return dim3((E + 3) / 4); };
    auto egrid = [](size_t total) {
        size_t g = (total + 255) / 256;
        return dim3((unsigned)(g > 2048 ? 2048 : g));
    };

    // ===================== weight fragment transforms (one kernel) ==========
    WtJobs jobs;
    jobs.W[0] = d_Wl;  jobs.out[0] = wf_d;   jobs.K[0] = 125; jobs.Nn[0] = 256; jobs.nnt[0] = 16; jobs.nkt[0] = 4;
    jobs.W[1] = p1_Wl; jobs.out[1] = wf_p1l; jobs.K[1] = 257; jobs.Nn[1] = 256; jobs.nnt[1] = 16; jobs.nkt[1] = 9;
    jobs.W[2] = p1_Wr; jobs.out[2] = wf_p1r; jobs.K[2] = 257; jobs.Nn[2] = 256; jobs.nnt[2] = 16; jobs.nkt[2] = 9;
    jobs.W[3] = p2_Wl; jobs.out[3] = wf_p2l; jobs.K[3] = 256; jobs.Nn[3] = 256; jobs.nnt[3] = 16; jobs.nkt[3] = 8;
    jobs.W[4] = p2_Wr; jobs.out[4] = wf_p2r; jobs.K[4] = 256; jobs.Nn[4] = 256; jobs.nnt[4] = 16; jobs.nkt[4] = 8;
    jobs.W[5] = p3_Wl; jobs.out[5] = wf_p3l; jobs.K[5] = 256; jobs.Nn[5] = 64;  jobs.nnt[5] = 4;  jobs.nkt[5] = 8;
    jobs.W[6] = p3_Wr; jobs.out[6] = wf_p3r; jobs.K[6] = 256; jobs.Nn[6] = 64;  jobs.nnt[6] = 4;  jobs.nkt[6] = 8;
    jobs.W[7] = pr_W1; jobs.out[7] = wf_pr1; jobs.K[7] = 64;  jobs.Nn[7] = 64;  jobs.nnt[7] = 4;  jobs.nkt[7] = 2;
    wt_frag_all<<<dim3(36, 8), blk, 0, stream>>>(jobs);
    cast_frag<<<dim3(320), blk, 0, stream>>>(xl, N_LOW, 125, xl_f, 320, 4);

    // ===================== combined CSR build ===============================
    hipMemsetAsync(cnt, 0, 2 * (size_t)N * sizeof(int), stream);
    hist_all<<<egrid(ETOT), blk, 0, stream>>>(di_lh, di_hh, cnt);
    scan_partial<<<dim3(NB2), blk, 0, stream>>>(cnt, off, bscan, 2 * N);
    scan_bsums<<<dim3(1), blk, 0, stream>>>(bscan, NB2, off, 2 * N);
    scan_add<<<dim3(NB2), blk, 0, stream>>>(off, bscan, 2 * N);
    hipMemcpyAsync(cur, off, 2 * (size_t)N * sizeof(int), hipMemcpyDeviceToDevice, stream);
    scatter_all<<<egrid(ETOT), blk, 0, stream>>>(si_lh, di_lh, si_hh, di_hh, cur, csr);

    // ===================== d layer (low -> high, H=1, C=256) ================
    gemm_mfma<false, true><<<dim3(4, 40), blk, 0, stream>>>(xl_f, wf_d, d_bl, hl, N_LOW, 256, 4);
    gat_gather<1, 256, true><<<wgrid(N), blk, 0, stream>>>(
        hl16, nullptr, xh, d_Wr, d_br, rp_lh, csr, d_att, d_b, xA16, 264, 1, N, zstd);

    // ===================== bn0 + frag cast (stride 264, F=257) =============
    hipMemsetAsync(bsum, 0, 528 * sizeof(float), stream);
    bn_partial3<33, 7><<<dim3(RBLK), blk, 0, stream>>>(xA16, N, partials);
    bn_reduce2<<<dim3(9, 32), blk, 0, stream>>>(partials, 528, bsum);
    bn_frag<false><<<dim3(2048), blk, 0, stream>>>(xA16, N, 257, 264, 264, bsum, bn0_g, bn0_b, AfB, NMT, 9);

    // ===================== p1 (H=4, C=64) ===================================
    gemm_mfma2<<<dim3(4, 391, 2), blk, 0, stream>>>(AfB, wf_p1l, wf_p1r, p1_bl, p1_br, hl, hr, N, 256, 9);
    gat_gather<4, 64, false><<<wgrid(N), blk, 0, stream>>>(
        hl16, hr16, nullptr, nullptr, nullptr, rp_hh, csr, p1_att, p1_b, xB16, 256, 0, N, nullptr);
    hipMemsetAsync(bsum, 0, 512 * sizeof(float), stream);
    bn_partial3<32, 8><<<dim3(RBLK), blk, 0, stream>>>(xB16, N, partials);
    bn_reduce2<<<dim3(8, 32), blk, 0, stream>>>(partials, 512, bsum);
    bn_frag<true><<<dim3(2048), blk, 0, stream>>>(xB16, N, 256, 256, 256, bsum, bn1_g, bn1_b, AfA, NMT, 8);

    // ===================== p2 (H=4, C=64) ===================================
    gemm_mfma2<<<dim3(4, 391, 2), blk, 0, stream>>>(AfA, wf_p2l, wf_p2r, p2_bl, p2_br, hl, hr, N, 256, 8);
    gat_gather<4, 64, false><<<wgrid(N), blk, 0, stream>>>(
        hl16, hr16, nullptr, nullptr, nullptr, rp_hh, csr, p2_att, p2_b, xA16, 256, 0, N, nullptr);
    hipMemsetAsync(bsum, 0, 512 * sizeof(float), stream);
    bn_partial3<32, 8><<<dim3(RBLK), blk, 0, stream>>>(xA16, N, partials);
    bn_reduce2<<<dim3(8, 32), blk, 0, stream>>>(partials, 512, bsum);
    bn_frag<true><<<dim3(2048), blk, 0, stream>>>(xA16, N, 256, 256, 256, bsum, bn2_g, bn2_b, AfB, NMT, 8);

    // ===================== p3 (H=1, C=64) ===================================
    gemm_mfma2<<<dim3(1, 391, 2), blk, 0, stream>>>(AfB, wf_p3l, wf_p3r, p3_bl, p3_br, hl, hr, N, 64, 8);
    gat_gather<1, 64, false><<<wgrid(N), blk, 0, stream>>>(
        hl16, hr16, nullptr, nullptr, nullptr, rp_hh, csr, p3_att, p3_b, xB16, 64, 0, N, nullptr);
    hipMemsetAsync(bsum, 0, 128 * sizeof(float), stream);
    bn_partial3<8, 32><<<dim3(RBLK), blk, 0, stream>>>(xB16, N, partials);
    bn_reduce2<<<dim3(2, 32), blk, 0, stream>>>(partials, 128, bsum);
    bn_frag<true><<<dim3(2048), blk, 0, stream>>>(xB16, N, 64, 64, 64, bsum, bn3_g, bn3_b, AfA, NMT, 2);

    // ===================== predictor MLP ====================================
    gemm_mfma<true, false><<<dim3(1, 391), blk, 0, stream>>>(AfA, wf_pr1, pr_b1, hl, N, 64, 2);
    dot_w2<<<wgrid(N), blk, 0, stream>>>(hl, pr_W2, pr_b2, y, N);
}